// Round 4
// baseline (205.130 us; speedup 1.0000x reference)
//
#include <hip/hip_runtime.h>
#include <cstddef>
#include <cstdint>

#define T_DIM 2048
#define E_DIM 1024
#define M_DIM 4096   // T*B rows, row index = t*2 + b

typedef __attribute__((ext_vector_type(8))) short short8;      // 8 fp16 bit-patterns
typedef __attribute__((ext_vector_type(8))) _Float16 half8;    // mfma f16 A/B (x32)
typedef __attribute__((ext_vector_type(4))) _Float16 half4;    // mfma f16 A/B (x16)
typedef __attribute__((ext_vector_type(4))) float f32x4;       // mfma C/D

__device__ __forceinline__ short f16_bits(float v) {
  return __builtin_bit_cast(short, (_Float16)v);
}
__device__ __forceinline__ unsigned int pk2(float a, float b) {
  return __builtin_bit_cast(unsigned int, __builtin_amdgcn_cvt_pkrtz(a, b));
}
__device__ __forceinline__ half8 h8(short8 s) { return __builtin_bit_cast(half8, s); }

// async global->LDS, 16B per lane; LDS dest = wave-uniform base + lane*16
__device__ __forceinline__ void gl_lds16(const short* g, const short* l) {
  __builtin_amdgcn_global_load_lds(
      (const __attribute__((address_space(1))) unsigned int*)g,
      (__attribute__((address_space(3))) unsigned int*)l, 16, 0, 0);
}

// ---------------------------------------------------------------------------
// fp32 -> fp16 (RNE). blocks: [0,4096) x ; then 1024 each wq, wk, wv, wo.
// ---------------------------------------------------------------------------
__global__ __launch_bounds__(256) void convert_all(
    const float* __restrict__ x, const float* __restrict__ wq,
    const float* __restrict__ wk, const float* __restrict__ wv,
    const float* __restrict__ wo,
    short* __restrict__ xh, short* __restrict__ wqh, short* __restrict__ wkh,
    short* __restrict__ wvh, short* __restrict__ woh)
{
  const int bid = blockIdx.x;
  const float* in; short* hi; int base;
  if (bid < 4096)      { in = x;  hi = xh;  base = 0;    }
  else if (bid < 5120) { in = wq; hi = wqh; base = 4096; }
  else if (bid < 6144) { in = wk; hi = wkh; base = 5120; }
  else if (bid < 7168) { in = wv; hi = wvh; base = 6144; }
  else                 { in = wo; hi = woh; base = 7168; }
  const int i = (bid - base) * 256 + threadIdx.x;     // float4 index
  float4 v = ((const float4*)in)[i];
  uint2 p;
  p.x = (unsigned short)f16_bits(v.x) | ((unsigned int)(unsigned short)f16_bits(v.y) << 16);
  p.y = (unsigned short)f16_bits(v.z) | ((unsigned int)(unsigned short)f16_bits(v.w) << 16);
  ((uint2*)hi)[i] = p;
}

// ---------------------------------------------------------------------------
// Fused QKV GEMM, fp16, BK=64 (round-2 proven version). V emitted d-major
// ([bh][d][T]) via the Tb transpose epilogue.
// ---------------------------------------------------------------------------
__global__ __launch_bounds__(256) void gemm_qkv(
    const short* __restrict__ xh,
    const short* __restrict__ wqh, const short* __restrict__ wkh,
    const short* __restrict__ wvh,
    const float* __restrict__ bq, const float* __restrict__ bk,
    const float* __restrict__ bv,
    short* __restrict__ qo, short* __restrict__ ko, short* __restrict__ vto)
{
  __shared__ __align__(16) short smem[128 * 64 * 2];   // Ah | Wh ; Tb overlays
  short* Ah = smem;
  short* Wh = smem + 8192;
  const int tid = threadIdx.x;
  const int lane = tid & 63;
  const int w = tid >> 6;
  const int quad = lane >> 4;
  const int l15 = lane & 15;
  const int sel = blockIdx.x >> 3;
  const int n0 = (blockIdx.x & 7) * 128;
  const int m0 = blockIdx.y * 128;

  const short* wsel = sel == 0 ? wqh : sel == 1 ? wkh : wvh;
  const float* bias = sel == 0 ? bq : sel == 1 ? bk : bv;
  const float scale = sel == 0 ? 0.125f * 1.44269504088896f : 1.0f;

  const short* gsrc = (w < 2) ? xh : wsel;
  short* lbuf = (w < 2) ? Ah : Wh;
  const int rbase = (w < 2) ? m0 : n0;
  const int lrow8 = lane >> 3;
  const int gph8 = lane & 7;
  const int kg = (gph8 - lrow8) & 7;    // global k-group this lane stages

  f32x4 zero = {0.f, 0.f, 0.f, 0.f};
  f32x4 acc[4][4];
#pragma unroll
  for (int i = 0; i < 4; ++i)
#pragma unroll
    for (int j = 0; j < 4; ++j) acc[i][j] = zero;

  const int wm = w & 1, wn = w >> 1;

  for (int k0 = 0; k0 < E_DIM; k0 += 64) {
    __syncthreads();
#pragma unroll
    for (int jj = 0; jj < 8; ++jj) {
      int j = (w & 1) * 8 + jj;       // 16 staging insts per matrix, 2 waves
      int r = j * 8 + lrow8;          // 0..127
      gl_lds16(gsrc + (size_t)(rbase + r) * E_DIM + k0 + kg * 8, lbuf + j * 512);
    }
    __syncthreads();
#pragma unroll
    for (int ks = 0; ks < 2; ++ks) {
      short8 ahf[4];
#pragma unroll
      for (int i = 0; i < 4; ++i) {
        int r = wm * 64 + i * 16 + l15;
        ahf[i] = *(const short8*)&Ah[r * 64 + ((ks * 4 + quad + r) & 7) * 8];
      }
#pragma unroll
      for (int j = 0; j < 4; ++j) {
        int r = wn * 64 + j * 16 + l15;
        short8 bhf = *(const short8*)&Wh[r * 64 + ((ks * 4 + quad + r) & 7) * 8];
#pragma unroll
        for (int i = 0; i < 4; ++i)
          acc[i][j] = __builtin_amdgcn_mfma_f32_16x16x32_f16(h8(ahf[i]), h8(bhf), acc[i][j], 0, 0, 0);
      }
    }
  }

  if (sel < 2) {
#pragma unroll
    for (int j = 0; j < 4; ++j) {
      const int gc = n0 + wn * 64 + j * 16 + l15;
      const float bb = bias[gc];
      const int h = gc >> 6, d = gc & 63;
      short* dst = sel == 0 ? qo : ko;
#pragma unroll
      for (int i = 0; i < 4; ++i)
#pragma unroll
        for (int reg = 0; reg < 4; ++reg) {
          const int gm = m0 + wm * 64 + i * 16 + quad * 4 + reg;
          const float val = (acc[i][j][reg] + bb) * scale;
          const int t = gm >> 1, b = gm & 1;
          dst[((size_t)(b * 16 + h) * T_DIM + t) * 64 + d] = f16_bits(val);
        }
    }
  } else {
    short* Tb = smem;   // 64 * 128 * 2B = 16KB
    const int by = blockIdx.y;
#pragma unroll
    for (int R = 0; R < 2; ++R) {
      __syncthreads();
      if (wn == R) {
#pragma unroll
        for (int j = 0; j < 4; ++j) {
          const int nl = j * 16 + l15;
          const int gc = n0 + R * 64 + nl;
          const float bb = bias[gc];
#pragma unroll
          for (int i = 0; i < 4; ++i) {
            const int tp = wm * 32 + i * 8 + quad * 2;        // t' base (even)
            unsigned int lo = pk2(acc[i][j][0] + bb, acc[i][j][2] + bb);
            unsigned int hi = pk2(acc[i][j][1] + bb, acc[i][j][3] + bb);
            const int g0 = tp >> 3;
            const int sub = tp & 7;
            *(unsigned int*)&Tb[nl * 128 + ((g0 + nl) & 15) * 8 + sub] = lo;
            *(unsigned int*)&Tb[nl * 128 + ((g0 + 8 + nl) & 15) * 8 + sub] = hi;
          }
        }
      }
      __syncthreads();
#pragma unroll
      for (int ii = 0; ii < 4; ++ii) {
        const int n = w * 16 + ii * 4 + quad;
        const int g = (l15 - n) & 15;
        short8 vvec = *(const short8*)&Tb[n * 128 + l15 * 8];
        const int gc = n0 + R * 64 + n;
        const int h = gc >> 6, d = gc & 63;
        const int b = g >> 3;
        const int t = by * 64 + (g & 7) * 8;
        *(short8*)&vto[((size_t)(b * 16 + h) * 64 + d) * T_DIM + t] = vvec;
      }
    }
  }
}

// ---------------------------------------------------------------------------
// Output projection, fused split-K: 512 threads = 2 groups x 4 waves.
// ---------------------------------------------------------------------------
__global__ __launch_bounds__(512, 4) void gemm_out_fused(
    const short* __restrict__ attn, const short* __restrict__ woh,
    const float* __restrict__ bo, float* __restrict__ out)
{
  __shared__ __align__(16) short smem[32768];   // 64 KB: [g][Ah 16KB | Wh 16KB]
  const int tid = threadIdx.x;
  const int lane = tid & 63;
  const int w = tid >> 6;         // 0..7
  const int g = w >> 2;           // K-half group
  const int wg = w & 3;
  const int quad = lane >> 4;
  const int l15 = lane & 15;
  const int n0 = blockIdx.x * 128;
  const int m0 = blockIdx.y * 128;

  short* Ah = smem + g * 16384;
  short* Wh = Ah + 8192;
  const short* gsrc = (wg < 2) ? attn : woh;
  short* lbuf = (wg < 2) ? Ah : Wh;
  const int rbase = (wg < 2) ? m0 : n0;
  const int lrow8 = lane >> 3;
  const int gph8 = lane & 7;
  const int kg = (gph8 - lrow8) & 7;

  f32x4 zero = {0.f, 0.f, 0.f, 0.f};
  f32x4 acc[4][4];
#pragma unroll
  for (int i = 0; i < 4; ++i)
#pragma unroll
    for (int j = 0; j < 4; ++j) acc[i][j] = zero;

  const int wm = wg & 1, wn = wg >> 1;

  for (int k0 = g * 512; k0 < g * 512 + 512; k0 += 64) {
    __syncthreads();
#pragma unroll
    for (int jj = 0; jj < 8; ++jj) {
      int j = (wg & 1) * 8 + jj;
      int r = j * 8 + lrow8;
      gl_lds16(gsrc + (size_t)(rbase + r) * E_DIM + k0 + kg * 8, lbuf + j * 512);
    }
    __syncthreads();
#pragma unroll
    for (int ks = 0; ks < 2; ++ks) {
      short8 ahf[4];
#pragma unroll
      for (int i = 0; i < 4; ++i) {
        int r = wm * 64 + i * 16 + l15;
        ahf[i] = *(const short8*)&Ah[r * 64 + ((ks * 4 + quad + r) & 7) * 8];
      }
#pragma unroll
      for (int j = 0; j < 4; ++j) {
        int r = wn * 64 + j * 16 + l15;
        short8 bhf = *(const short8*)&Wh[r * 64 + ((ks * 4 + quad + r) & 7) * 8];
#pragma unroll
        for (int i = 0; i < 4; ++i)
          acc[i][j] = __builtin_amdgcn_mfma_f32_16x16x32_f16(h8(ahf[i]), h8(bhf), acc[i][j], 0, 0, 0);
      }
    }
  }

  // ---- cross-group combine via 64 KB LDS scratch ----
  __syncthreads();
  f32x4* Osc = (f32x4*)smem;           // 4096 f32x4
  if (g == 1) {
    f32x4* dst = Osc + wg * 1024;      // 16 KB per wg
#pragma unroll
    for (int i = 0; i < 4; ++i)
#pragma unroll
      for (int j = 0; j < 4; ++j)
        dst[(i * 4 + j) * 64 + lane] = acc[i][j];
  }
  __syncthreads();
  if (g == 0) {
    f32x4* src = Osc + wg * 1024;
#pragma unroll
    for (int j = 0; j < 4; ++j) {
      const int gc = n0 + wn * 64 + j * 16 + l15;
      const float bb = bo[gc];
#pragma unroll
      for (int i = 0; i < 4; ++i) {
        f32x4 t = src[(i * 4 + j) * 64 + lane];
#pragma unroll
        for (int reg = 0; reg < 4; ++reg) {
          const int gm = m0 + wm * 64 + i * 16 + quad * 4 + reg;
          out[(size_t)gm * E_DIM + gc] = acc[i][j][reg] + t[reg] + bb;
        }
      }
    }
  }
}

// ---------------------------------------------------------------------------
// Flash attention v7 — q-split restructure for occupancy.
// Post-mortems r0-r3: FETCH 70->12MB, conflicts 3.3M->131K, HBM 1.5->0.4 TB/s
// and dur never moved off ~52us -> not memory-bound; latency-bound at
// 2 waves/SIMD (acc[4][8]+qa[8][2] ~190 unified regs capped occupancy).
// v7: wave owns 16 q-rows x ALL s (was: all q x private 16-s slice).
//  - acc 128->16 regs, qa 64->8 regs (~100 unified/wave).
//  - O-reduce epilogue + 64KB Osc + l_red deleted (waves output-independent).
//  - QBLK=64 -> grid (32,32)=1024 blocks; LDS 32KB (ring-2 shared K/V 16KB
//    slots, Qs overlaid in slot1) -> 4 blocks/CU, 16 waves/CU, 4 waves/SIMD.
//  - 1 barrier/chunk (shared slots, ring-2); prefetch chunk c+1 right after
//    the barrier, drained by next iteration's barrier (1 chunk of compute to
//    hide L2 latency).
//  - V d-major ([bh][d][T], round-2 proven); V LDS rows now 128B so columns
//    are XOR-rotated via pre-swizzled global source (col8 = (g + d) & 7).
//  - XCD remap kept: fid%8 = XCD -> 4 bh per XCD (~2MB K/V, L2-resident).
// ---------------------------------------------------------------------------
__global__ __launch_bounds__(256, 4) void attn_mfma(
    const short* __restrict__ q, const short* __restrict__ k,
    const short* __restrict__ vt, short* __restrict__ attn)
{
  __shared__ __align__(16) short SMEM[16384];   // 32 KB: ring[2] x (K 8KB | V 8KB)
  short* Qs = SMEM + 8192;     // overlays slot 1 K-region; dead after qa load

  const int tid = threadIdx.x;
  const int lane = tid & 63;
  const int w = tid >> 6;
  const int quad = lane >> 4;
  const int l15 = lane & 15;

  // XCD-aware remap: XCD = fid%8 -> bh {x, x+8, x+16, x+24} on XCD x.
  const int fid = blockIdx.y * 32 + blockIdx.x;
  const int bhid = fid & 31;
  const int t0 = (fid >> 5) * 64;
  const int b = bhid >> 4, h = bhid & 15;

  const short* qb = q + (size_t)bhid * T_DIM * 64;
  const short* kb = k + (size_t)bhid * T_DIM * 64;
  const short* vb = vt + (size_t)bhid * 64 * T_DIM;   // d-major

  const int lrow8 = lane >> 3;
  const int gph8 = lane & 7;
  const int kg = (gph8 - lrow8) & 7;

  // ---- stage Q tile [64][64] (8 KB) into Qs ----
#pragma unroll
  for (int jj = 0; jj < 2; ++jj) {
    int j = w * 2 + jj;
    int r = j * 8 + lrow8;
    int gl = (gph8 - (r >> 1)) & 7;
    gl_lds16(qb + (size_t)(t0 + r) * 64 + gl * 8, Qs + j * 512);
  }
  // ---- stage chunk 0 into slot 0: K [64 s][64 d] + V [64 d][64 s] ----
#pragma unroll
  for (int jj = 0; jj < 2; ++jj) {
    const int row = w * 16 + jj * 8 + lrow8;       // s-row for K, d-row for V
    gl_lds16(kb + (size_t)row * 64 + kg * 8, SMEM + (w * 16 + jj * 8) * 64);
    gl_lds16(vb + (size_t)row * T_DIM + kg * 8, SMEM + 4096 + (w * 16 + jj * 8) * 64);
  }
  __syncthreads();

  // ---- register-cache this wave's Q B-fragments (16 q-rows) ----
  short8 qa[2];
  {
    const int r = w * 16 + l15;
#pragma unroll
    for (int st = 0; st < 2; ++st)
      qa[st] = *(const short8*)&Qs[r * 64 + ((st * 4 + quad + (r >> 1)) & 7) * 8];
  }
  __syncthreads();   // all qa reads done before slot1 (Qs) is overwritten

  const f32x4 zero = {0.f, 0.f, 0.f, 0.f};
  f32x4 acc[4];
#pragma unroll
  for (int d = 0; d < 4; ++d) acc[d] = zero;
  float lp = 0.f;

  for (int c = 0; c < 32; ++c) {
    if (c > 0) __syncthreads();       // chunk c staged & visible; prev reads done
    if (c < 31) {                     // prefetch chunk c+1 into slot (c+1)&1
      short* ns = SMEM + ((c + 1) & 1) * 8192;
#pragma unroll
      for (int jj = 0; jj < 2; ++jj) {
        const int row = w * 16 + jj * 8 + lrow8;
        gl_lds16(kb + (size_t)((c + 1) * 64 + row) * 64 + kg * 8,
                 ns + (w * 16 + jj * 8) * 64);
        gl_lds16(vb + (size_t)row * T_DIM + (c + 1) * 64 + kg * 8,
                 ns + 4096 + (w * 16 + jj * 8) * 64);
      }
    }
    const short* slot = SMEM + (c & 1) * 8192;

    __builtin_amdgcn_s_setprio(1);
    uint2 pb[4];
#pragma unroll
    for (int stile = 0; stile < 4; ++stile) {
      const int kr = (stile * 16 + l15) * 64;
      short8 kf0 = *(const short8*)&slot[kr + ((quad + l15) & 7) * 8];
      short8 kf1 = *(const short8*)&slot[kr + ((4 + quad + l15) & 7) * 8];
      f32x4 s = zero;
      s = __builtin_amdgcn_mfma_f32_16x16x32_f16(h8(kf0), h8(qa[0]), s, 0, 0, 0);
      s = __builtin_amdgcn_mfma_f32_16x16x32_f16(h8(kf1), h8(qa[1]), s, 0, 0, 0);
      float p0 = __builtin_amdgcn_exp2f(s[0]);
      float p1 = __builtin_amdgcn_exp2f(s[1]);
      float p2 = __builtin_amdgcn_exp2f(s[2]);
      float p3 = __builtin_amdgcn_exp2f(s[3]);
      lp += (p0 + p1) + (p2 + p3);
      pb[stile].x = pk2(p0, p1);
      pb[stile].y = pk2(p2, p3);
    }

#pragma unroll
    for (int stile = 0; stile < 4; ++stile) {
      const int g = stile * 2 + (quad >> 1);
#pragma unroll
      for (int dblk = 0; dblk < 4; ++dblk) {
        uint2 va = *(const uint2*)&slot[4096 + (dblk * 16 + l15) * 64 +
                                        ((g + l15) & 7) * 8 + (quad & 1) * 4];
        acc[dblk] = __builtin_amdgcn_mfma_f32_16x16x16f16(
            __builtin_bit_cast(half4, va), __builtin_bit_cast(half4, pb[stile]),
            acc[dblk], 0, 0, 0);
      }
    }
    __builtin_amdgcn_s_setprio(0);
  }

  // ---- l reduce over quad groups (lanes sharing l15) ----
  lp += __shfl_xor(lp, 16);
  lp += __shfl_xor(lp, 32);
  const float inv = 1.f / lp;

  // ---- store: lane holds O[q = w*16+l15][d = dblk*16 + quad*4 + reg] ----
  const int t = t0 + w * 16 + l15;
  const size_t mrow = (size_t)(t * 2 + b) * E_DIM;
#pragma unroll
  for (int dblk = 0; dblk < 4; ++dblk) {
    uint2 ov;
    ov.x = pk2(acc[dblk][0] * inv, acc[dblk][1] * inv);
    ov.y = pk2(acc[dblk][2] * inv, acc[dblk][3] * inv);
    *(uint2*)&attn[mrow + h * 64 + dblk * 16 + quad * 4] = ov;
  }
}

// ---------------------------------------------------------------------------
extern "C" void kernel_launch(void* const* d_in, const int* in_sizes, int n_in,
                              void* d_out, int out_size, void* d_ws, size_t ws_size,
                              hipStream_t stream)
{
  const float* x  = (const float*)d_in[0];
  const float* wq = (const float*)d_in[1];
  const float* bq = (const float*)d_in[2];
  const float* wk = (const float*)d_in[3];
  const float* bk = (const float*)d_in[4];
  const float* wv = (const float*)d_in[5];
  const float* bv = (const float*)d_in[6];
  const float* wo = (const float*)d_in[7];
  const float* bo = (const float*)d_in[8];
  float* out = (float*)d_out;

  short* ws = (short*)d_ws;
  const size_t M4 = (size_t)M_DIM * E_DIM;   // 4M elems
  const size_t M1 = (size_t)E_DIM * E_DIM;   // 1M elems
  short* aws  = ws;          // attn out fp16, live until gemm_out
  short* woh  = aws + M4;    // wo fp16, live until gemm_out
  short* xh   = woh + M1;
  short* wqh  = xh + M4;
  short* wkh  = wqh + M1;
  short* wvh  = wkh + M1;
  short* qws  = wvh + M1;
  short* kws  = qws + M4;
  short* vtws = kws + M4;    // end = 24M shorts = 48 MB

  convert_all<<<8192, 256, 0, stream>>>(x, wq, wk, wv, wo, xh, wqh, wkh, wvh, woh);
  gemm_qkv<<<dim3(24, 32), 256, 0, stream>>>(xh, wqh, wkh, wvh, bq, bk, bv,
                                             qws, kws, vtws);
  attn_mfma<<<dim3(32, 32), 256, 0, stream>>>(qws, kws, vtws, aws);
  gemm_out_fused<<<dim3(8, 32), 512, 0, stream>>>(aws, woh, bo, out);
}

// Round 5
// 204.080 us; speedup vs baseline: 1.0051x; 1.0051x over previous
//
#include <hip/hip_runtime.h>
#include <cstddef>
#include <cstdint>

#define T_DIM 2048
#define E_DIM 1024
#define M_DIM 4096   // T*B rows, row index = t*2 + b

typedef __attribute__((ext_vector_type(8))) short short8;      // 8 fp16 bit-patterns
typedef __attribute__((ext_vector_type(8))) _Float16 half8;    // mfma f16 A/B (x32)
typedef __attribute__((ext_vector_type(4))) _Float16 half4;    // mfma f16 A/B (x16)
typedef __attribute__((ext_vector_type(4))) float f32x4;       // mfma C/D

__device__ __forceinline__ short f16_bits(float v) {
  return __builtin_bit_cast(short, (_Float16)v);
}
__device__ __forceinline__ unsigned int pk2(float a, float b) {
  return __builtin_bit_cast(unsigned int, __builtin_amdgcn_cvt_pkrtz(a, b));
}
__device__ __forceinline__ half8 h8(short8 s) { return __builtin_bit_cast(half8, s); }

// async global->LDS, 16B per lane; LDS dest = wave-uniform base + lane*16
__device__ __forceinline__ void gl_lds16(const short* g, const short* l) {
  __builtin_amdgcn_global_load_lds(
      (const __attribute__((address_space(1))) unsigned int*)g,
      (__attribute__((address_space(3))) unsigned int*)l, 16, 0, 0);
}

// ---------------------------------------------------------------------------
// fp32 -> fp16 (RNE). blocks: [0,4096) x ; then 1024 each wq, wk, wv, wo.
// ---------------------------------------------------------------------------
__global__ __launch_bounds__(256) void convert_all(
    const float* __restrict__ x, const float* __restrict__ wq,
    const float* __restrict__ wk, const float* __restrict__ wv,
    const float* __restrict__ wo,
    short* __restrict__ xh, short* __restrict__ wqh, short* __restrict__ wkh,
    short* __restrict__ wvh, short* __restrict__ woh)
{
  const int bid = blockIdx.x;
  const float* in; short* hi; int base;
  if (bid < 4096)      { in = x;  hi = xh;  base = 0;    }
  else if (bid < 5120) { in = wq; hi = wqh; base = 4096; }
  else if (bid < 6144) { in = wk; hi = wkh; base = 5120; }
  else if (bid < 7168) { in = wv; hi = wvh; base = 6144; }
  else                 { in = wo; hi = woh; base = 7168; }
  const int i = (bid - base) * 256 + threadIdx.x;     // float4 index
  float4 v = ((const float4*)in)[i];
  uint2 p;
  p.x = (unsigned short)f16_bits(v.x) | ((unsigned int)(unsigned short)f16_bits(v.y) << 16);
  p.y = (unsigned short)f16_bits(v.z) | ((unsigned int)(unsigned short)f16_bits(v.w) << 16);
  ((uint2*)hi)[i] = p;
}

// ---------------------------------------------------------------------------
// Fused QKV GEMM, fp16, BK=64 (round-2 proven version). V emitted d-major
// ([bh][d][T]) via the Tb transpose epilogue.
// ---------------------------------------------------------------------------
__global__ __launch_bounds__(256) void gemm_qkv(
    const short* __restrict__ xh,
    const short* __restrict__ wqh, const short* __restrict__ wkh,
    const short* __restrict__ wvh,
    const float* __restrict__ bq, const float* __restrict__ bk,
    const float* __restrict__ bv,
    short* __restrict__ qo, short* __restrict__ ko, short* __restrict__ vto)
{
  __shared__ __align__(16) short smem[128 * 64 * 2];   // Ah | Wh ; Tb overlays
  short* Ah = smem;
  short* Wh = smem + 8192;
  const int tid = threadIdx.x;
  const int lane = tid & 63;
  const int w = tid >> 6;
  const int quad = lane >> 4;
  const int l15 = lane & 15;
  const int sel = blockIdx.x >> 3;
  const int n0 = (blockIdx.x & 7) * 128;
  const int m0 = blockIdx.y * 128;

  const short* wsel = sel == 0 ? wqh : sel == 1 ? wkh : wvh;
  const float* bias = sel == 0 ? bq : sel == 1 ? bk : bv;
  const float scale = sel == 0 ? 0.125f * 1.44269504088896f : 1.0f;

  const short* gsrc = (w < 2) ? xh : wsel;
  short* lbuf = (w < 2) ? Ah : Wh;
  const int rbase = (w < 2) ? m0 : n0;
  const int lrow8 = lane >> 3;
  const int gph8 = lane & 7;
  const int kg = (gph8 - lrow8) & 7;    // global k-group this lane stages

  f32x4 zero = {0.f, 0.f, 0.f, 0.f};
  f32x4 acc[4][4];
#pragma unroll
  for (int i = 0; i < 4; ++i)
#pragma unroll
    for (int j = 0; j < 4; ++j) acc[i][j] = zero;

  const int wm = w & 1, wn = w >> 1;

  for (int k0 = 0; k0 < E_DIM; k0 += 64) {
    __syncthreads();
#pragma unroll
    for (int jj = 0; jj < 8; ++jj) {
      int j = (w & 1) * 8 + jj;       // 16 staging insts per matrix, 2 waves
      int r = j * 8 + lrow8;          // 0..127
      gl_lds16(gsrc + (size_t)(rbase + r) * E_DIM + k0 + kg * 8, lbuf + j * 512);
    }
    __syncthreads();
#pragma unroll
    for (int ks = 0; ks < 2; ++ks) {
      short8 ahf[4];
#pragma unroll
      for (int i = 0; i < 4; ++i) {
        int r = wm * 64 + i * 16 + l15;
        ahf[i] = *(const short8*)&Ah[r * 64 + ((ks * 4 + quad + r) & 7) * 8];
      }
#pragma unroll
      for (int j = 0; j < 4; ++j) {
        int r = wn * 64 + j * 16 + l15;
        short8 bhf = *(const short8*)&Wh[r * 64 + ((ks * 4 + quad + r) & 7) * 8];
#pragma unroll
        for (int i = 0; i < 4; ++i)
          acc[i][j] = __builtin_amdgcn_mfma_f32_16x16x32_f16(h8(ahf[i]), h8(bhf), acc[i][j], 0, 0, 0);
      }
    }
  }

  if (sel < 2) {
#pragma unroll
    for (int j = 0; j < 4; ++j) {
      const int gc = n0 + wn * 64 + j * 16 + l15;
      const float bb = bias[gc];
      const int h = gc >> 6, d = gc & 63;
      short* dst = sel == 0 ? qo : ko;
#pragma unroll
      for (int i = 0; i < 4; ++i)
#pragma unroll
        for (int reg = 0; reg < 4; ++reg) {
          const int gm = m0 + wm * 64 + i * 16 + quad * 4 + reg;
          const float val = (acc[i][j][reg] + bb) * scale;
          const int t = gm >> 1, b = gm & 1;
          dst[((size_t)(b * 16 + h) * T_DIM + t) * 64 + d] = f16_bits(val);
        }
    }
  } else {
    short* Tb = smem;   // 64 * 128 * 2B = 16KB
    const int by = blockIdx.y;
#pragma unroll
    for (int R = 0; R < 2; ++R) {
      __syncthreads();
      if (wn == R) {
#pragma unroll
        for (int j = 0; j < 4; ++j) {
          const int nl = j * 16 + l15;
          const int gc = n0 + R * 64 + nl;
          const float bb = bias[gc];
#pragma unroll
          for (int i = 0; i < 4; ++i) {
            const int tp = wm * 32 + i * 8 + quad * 2;        // t' base (even)
            unsigned int lo = pk2(acc[i][j][0] + bb, acc[i][j][2] + bb);
            unsigned int hi = pk2(acc[i][j][1] + bb, acc[i][j][3] + bb);
            const int g0 = tp >> 3;
            const int sub = tp & 7;
            *(unsigned int*)&Tb[nl * 128 + ((g0 + nl) & 15) * 8 + sub] = lo;
            *(unsigned int*)&Tb[nl * 128 + ((g0 + 8 + nl) & 15) * 8 + sub] = hi;
          }
        }
      }
      __syncthreads();
#pragma unroll
      for (int ii = 0; ii < 4; ++ii) {
        const int n = w * 16 + ii * 4 + quad;
        const int g = (l15 - n) & 15;
        short8 vvec = *(const short8*)&Tb[n * 128 + l15 * 8];
        const int gc = n0 + R * 64 + n;
        const int h = gc >> 6, d = gc & 63;
        const int b = g >> 3;
        const int t = by * 64 + (g & 7) * 8;
        *(short8*)&vto[((size_t)(b * 16 + h) * 64 + d) * T_DIM + t] = vvec;
      }
    }
  }
}

// ---------------------------------------------------------------------------
// Output projection, fused split-K: 512 threads = 2 groups x 4 waves.
// ---------------------------------------------------------------------------
__global__ __launch_bounds__(512, 4) void gemm_out_fused(
    const short* __restrict__ attn, const short* __restrict__ woh,
    const float* __restrict__ bo, float* __restrict__ out)
{
  __shared__ __align__(16) short smem[32768];   // 64 KB: [g][Ah 16KB | Wh 16KB]
  const int tid = threadIdx.x;
  const int lane = tid & 63;
  const int w = tid >> 6;         // 0..7
  const int g = w >> 2;           // K-half group
  const int wg = w & 3;
  const int quad = lane >> 4;
  const int l15 = lane & 15;
  const int n0 = blockIdx.x * 128;
  const int m0 = blockIdx.y * 128;

  short* Ah = smem + g * 16384;
  short* Wh = Ah + 8192;
  const short* gsrc = (wg < 2) ? attn : woh;
  short* lbuf = (wg < 2) ? Ah : Wh;
  const int rbase = (wg < 2) ? m0 : n0;
  const int lrow8 = lane >> 3;
  const int gph8 = lane & 7;
  const int kg = (gph8 - lrow8) & 7;

  f32x4 zero = {0.f, 0.f, 0.f, 0.f};
  f32x4 acc[4][4];
#pragma unroll
  for (int i = 0; i < 4; ++i)
#pragma unroll
    for (int j = 0; j < 4; ++j) acc[i][j] = zero;

  const int wm = wg & 1, wn = wg >> 1;

  for (int k0 = g * 512; k0 < g * 512 + 512; k0 += 64) {
    __syncthreads();
#pragma unroll
    for (int jj = 0; jj < 8; ++jj) {
      int j = (wg & 1) * 8 + jj;
      int r = j * 8 + lrow8;
      gl_lds16(gsrc + (size_t)(rbase + r) * E_DIM + k0 + kg * 8, lbuf + j * 512);
    }
    __syncthreads();
#pragma unroll
    for (int ks = 0; ks < 2; ++ks) {
      short8 ahf[4];
#pragma unroll
      for (int i = 0; i < 4; ++i) {
        int r = wm * 64 + i * 16 + l15;
        ahf[i] = *(const short8*)&Ah[r * 64 + ((ks * 4 + quad + r) & 7) * 8];
      }
#pragma unroll
      for (int j = 0; j < 4; ++j) {
        int r = wn * 64 + j * 16 + l15;
        short8 bhf = *(const short8*)&Wh[r * 64 + ((ks * 4 + quad + r) & 7) * 8];
#pragma unroll
        for (int i = 0; i < 4; ++i)
          acc[i][j] = __builtin_amdgcn_mfma_f32_16x16x32_f16(h8(ahf[i]), h8(bhf), acc[i][j], 0, 0, 0);
      }
    }
  }

  // ---- cross-group combine via 64 KB LDS scratch ----
  __syncthreads();
  f32x4* Osc = (f32x4*)smem;           // 4096 f32x4
  if (g == 1) {
    f32x4* dst = Osc + wg * 1024;      // 16 KB per wg
#pragma unroll
    for (int i = 0; i < 4; ++i)
#pragma unroll
      for (int j = 0; j < 4; ++j)
        dst[(i * 4 + j) * 64 + lane] = acc[i][j];
  }
  __syncthreads();
  if (g == 0) {
    f32x4* src = Osc + wg * 1024;
#pragma unroll
    for (int j = 0; j < 4; ++j) {
      const int gc = n0 + wn * 64 + j * 16 + l15;
      const float bb = bo[gc];
#pragma unroll
      for (int i = 0; i < 4; ++i) {
        f32x4 t = src[(i * 4 + j) * 64 + lane];
#pragma unroll
        for (int reg = 0; reg < 4; ++reg) {
          const int gm = m0 + wm * 64 + i * 16 + quad * 4 + reg;
          out[(size_t)gm * E_DIM + gc] = acc[i][j][reg] + t[reg] + bb;
        }
      }
    }
  }
}

// ---------------------------------------------------------------------------
// Flash attention v8 — s-split (r0 structure) at QBLK=64 for occupancy.
// Accounting from r0-r4: q-split (v7) makes every wave read the full 16KB
// K/V tile -> 2.1GB total LDS reads ~= 40us floor (the v7 wall). s-split
// reads 4KB/wave/chunk (268MB total, ~5us) but r0's acc[4][8]+qa[8][2]
// (~190 regs) capped it at 2 waves/SIMD -> latency-bound 3900cyc/chunk.
// v8 = r0's exact index math at QBLK=64: acc[4][4]=64 + qa[4][2]=32 regs
// -> launch_bounds(256,3) -> 3 waves/SIMD; ring2 (wave-private slices,
// own-wave vmcnt(0), barrier-free loop) -> LDS 40KB.
// KEPT: XCD remap (fid%8=XCD, 4bh/XCD L2-resident), setprio, d-major V.
// ---------------------------------------------------------------------------
__global__ __launch_bounds__(256, 3) void attn_mfma(
    const short* __restrict__ q, const short* __restrict__ k,
    const short* __restrict__ vt, short* __restrict__ attn)
{
  __shared__ __align__(16) short SMEM[20480];  // 40KB: ring2[2][4w][2048] | Qs 4096
  short* KV = SMEM;                  // 16384 shorts
  short* Qs = SMEM + 16384;          // 4096 shorts; l_red overlays after loop
  float* l_red = (float*)(SMEM + 16384);   // [4][64]

  const int tid = threadIdx.x;
  const int lane = tid & 63;
  const int w = tid >> 6;
  const int quad = lane >> 4;
  const int l15 = lane & 15;

  // XCD-aware remap: XCD = fid%8 -> bh {x, x+8, x+16, x+24} on XCD x.
  const int fid = blockIdx.y * 32 + blockIdx.x;
  const int bhid = fid & 31;
  const int t0 = (fid >> 5) * 64;
  const int b = bhid >> 4, h = bhid & 15;

  const short* qb = q + (size_t)bhid * T_DIM * 64;
  const short* kb = k + (size_t)bhid * T_DIM * 64;
  const short* vb = vt + (size_t)bhid * 64 * T_DIM;   // d-major

  const int lrow8 = lane >> 3;
  const int gph8 = lane & 7;
  const int kg = (gph8 - lrow8) & 7;
  const int vd = lane >> 1, vh = lane & 1;

  // ---- stage Q tile [64][64] ----
#pragma unroll
  for (int jj = 0; jj < 2; ++jj) {
    int j = w * 2 + jj;
    int r = j * 8 + lrow8;
    int gl = (gph8 - (r >> 1)) & 7;
    gl_lds16(qb + (size_t)(t0 + r) * 64 + gl * 8, Qs + j * 512);
  }
  // ---- stage chunk 0 into ring slot 0 (wave-private 16-s slice) ----
  {
    short* slot = KV + w * 2048;
    const int sg = w * 16;
    gl_lds16(kb + (size_t)(sg + lrow8) * 64 + kg * 8, slot);
    gl_lds16(kb + (size_t)(sg + lrow8 + 8) * 64 + kg * 8, slot + 512);
    gl_lds16(vb + (size_t)vd * T_DIM + sg + vh * 8, slot + 1024);
    gl_lds16(vb + (size_t)(vd + 32) * T_DIM + sg + vh * 8, slot + 1536);
  }
  __syncthreads();

  // ---- register-cache Q B-fragments (4 qbk = 64 q-rows) ----
  short8 qa[4][2];
#pragma unroll
  for (int qbk = 0; qbk < 4; ++qbk)
#pragma unroll
    for (int st = 0; st < 2; ++st) {
      int r = qbk * 16 + l15;
      int idx = r * 64 + (((st * 4 + quad) + (r >> 1)) & 7) * 8;
      qa[qbk][st] = *(const short8*)&Qs[idx];
    }
  __syncthreads();   // all qa reads done before l_red overlays Qs

  const f32x4 zero = {0.f, 0.f, 0.f, 0.f};
  f32x4 acc[4][4];               // [dblk][qbk] : O^T partial over own s-subset
  float l_part[4];
#pragma unroll
  for (int d = 0; d < 4; ++d)
#pragma unroll
    for (int qb2 = 0; qb2 < 4; ++qb2) acc[d][qb2] = zero;
#pragma unroll
  for (int i = 0; i < 4; ++i) l_part[i] = 0.f;

  for (int c = 0; c < 32; ++c) {
    if (c > 0) __builtin_amdgcn_s_waitcnt(0x0F70);   // vmcnt(0): chunk c landed
    const short* slot = KV + (c & 1) * 8192 + w * 2048;

    short8 kf[2];
#pragma unroll
    for (int st = 0; st < 2; ++st)
      kf[st] = *(const short8*)&slot[l15 * 64 + (((st * 4 + quad) + l15) & 7) * 8];
    uint2 vfu[4];
#pragma unroll
    for (int dblk = 0; dblk < 4; ++dblk)
      vfu[dblk] = *(const uint2*)&slot[1024 + (dblk * 16 + l15) * 16 + quad * 4];

    if (c < 31) {                  // prefetch chunk c+1 into the other slot
      short* nslot = KV + ((c + 1) & 1) * 8192 + w * 2048;
      const int sg = (c + 1) * 64 + w * 16;
      gl_lds16(kb + (size_t)(sg + lrow8) * 64 + kg * 8, nslot);
      gl_lds16(kb + (size_t)(sg + lrow8 + 8) * 64 + kg * 8, nslot + 512);
      gl_lds16(vb + (size_t)vd * T_DIM + sg + vh * 8, nslot + 1024);
      gl_lds16(vb + (size_t)(vd + 32) * T_DIM + sg + vh * 8, nslot + 1536);
    }

    __builtin_amdgcn_s_setprio(1);
    uint2 pb[4];
#pragma unroll
    for (int qbk = 0; qbk < 4; ++qbk) {
      f32x4 s = zero;
      s = __builtin_amdgcn_mfma_f32_16x16x32_f16(h8(kf[0]), h8(qa[qbk][0]), s, 0, 0, 0);
      s = __builtin_amdgcn_mfma_f32_16x16x32_f16(h8(kf[1]), h8(qa[qbk][1]), s, 0, 0, 0);
      float p0 = __builtin_amdgcn_exp2f(s[0]);
      float p1 = __builtin_amdgcn_exp2f(s[1]);
      float p2 = __builtin_amdgcn_exp2f(s[2]);
      float p3 = __builtin_amdgcn_exp2f(s[3]);
      l_part[qbk] += (p0 + p1) + (p2 + p3);
      pb[qbk].x = pk2(p0, p1);
      pb[qbk].y = pk2(p2, p3);
    }

#pragma unroll
    for (int dblk = 0; dblk < 4; ++dblk) {
      half4 va = __builtin_bit_cast(half4, vfu[dblk]);
#pragma unroll
      for (int qbk = 0; qbk < 4; ++qbk)
        acc[dblk][qbk] = __builtin_amdgcn_mfma_f32_16x16x16f16(
            va, __builtin_bit_cast(half4, pb[qbk]), acc[dblk][qbk], 0, 0, 0);
    }
    __builtin_amdgcn_s_setprio(0);
  }

  // ---- l reduce over quads, publish per-wave (into Qs-overlay region) ----
#pragma unroll
  for (int qbk = 0; qbk < 4; ++qbk) {
    float l = l_part[qbk];
    l += __shfl_xor(l, 16);
    l += __shfl_xor(l, 32);
    if (quad == 0) l_red[w * 64 + qbk * 16 + l15] = l;
  }

  // ---- pairwise O reduce via 32 KB LDS scratch (overlays KV ring only) ----
  f32x4* Osc = (f32x4*)SMEM;     // 2048 f32x4 = 32 KB
  __syncthreads();               // all waves out of the main loop
  if (w & 1) {                   // w1 -> region0, w3 -> region1
    f32x4* dst = Osc + (w >> 1) * 1024;
#pragma unroll
    for (int dblk = 0; dblk < 4; ++dblk)
#pragma unroll
      for (int qbk = 0; qbk < 4; ++qbk)
        dst[(dblk * 4 + qbk) * 64 + lane] = acc[dblk][qbk];
  }
  __syncthreads();
  if (!(w & 1)) {                // w0 += region0 (all dblk), w2 += region1
    f32x4* src = Osc + (w >> 1) * 1024;
#pragma unroll
    for (int dblk = 0; dblk < 4; ++dblk)
#pragma unroll
      for (int qbk = 0; qbk < 4; ++qbk) {
        f32x4 t = src[(dblk * 4 + qbk) * 64 + lane];
        acc[dblk][qbk][0] += t[0]; acc[dblk][qbk][1] += t[1];
        acc[dblk][qbk][2] += t[2]; acc[dblk][qbk][3] += t[3];
      }
  }
  __syncthreads();
  // swap-publish: w2 gives its dblk 0,1 to w0; w0 gives its dblk 2,3 to w2
  if (w == 2) {
#pragma unroll
    for (int d2 = 0; d2 < 2; ++d2)
#pragma unroll
      for (int qbk = 0; qbk < 4; ++qbk)
        Osc[(d2 * 4 + qbk) * 64 + lane] = acc[d2][qbk];
  }
  if (w == 0) {
#pragma unroll
    for (int d2 = 0; d2 < 2; ++d2)
#pragma unroll
      for (int qbk = 0; qbk < 4; ++qbk)
        Osc[512 + (d2 * 4 + qbk) * 64 + lane] = acc[2 + d2][qbk];
  }
  __syncthreads();
  if (w == 0) {                  // stores dblk 0,1
#pragma unroll
    for (int qbk = 0; qbk < 4; ++qbk) {
      const int qq = qbk * 16 + l15;
      const float lsum = l_red[0 * 64 + qq] + l_red[1 * 64 + qq] +
                         l_red[2 * 64 + qq] + l_red[3 * 64 + qq];
      const float inv = 1.f / lsum;
      const int t = t0 + qq;
      const size_t mrow = (size_t)(t * 2 + b) * E_DIM;
#pragma unroll
      for (int d2 = 0; d2 < 2; ++d2) {
        f32x4 t4 = Osc[(d2 * 4 + qbk) * 64 + lane];
        uint2 ov;
        ov.x = pk2((acc[d2][qbk][0] + t4[0]) * inv, (acc[d2][qbk][1] + t4[1]) * inv);
        ov.y = pk2((acc[d2][qbk][2] + t4[2]) * inv, (acc[d2][qbk][3] + t4[3]) * inv);
        *(uint2*)&attn[mrow + h * 64 + d2 * 16 + quad * 4] = ov;
      }
    }
  }
  if (w == 2) {                  // stores dblk 2,3
#pragma unroll
    for (int qbk = 0; qbk < 4; ++qbk) {
      const int qq = qbk * 16 + l15;
      const float lsum = l_red[0 * 64 + qq] + l_red[1 * 64 + qq] +
                         l_red[2 * 64 + qq] + l_red[3 * 64 + qq];
      const float inv = 1.f / lsum;
      const int t = t0 + qq;
      const size_t mrow = (size_t)(t * 2 + b) * E_DIM;
#pragma unroll
      for (int d2 = 0; d2 < 2; ++d2) {
        f32x4 t4 = Osc[512 + (d2 * 4 + qbk) * 64 + lane];
        uint2 ov;
        ov.x = pk2((acc[2 + d2][qbk][0] + t4[0]) * inv, (acc[2 + d2][qbk][1] + t4[1]) * inv);
        ov.y = pk2((acc[2 + d2][qbk][2] + t4[2]) * inv, (acc[2 + d2][qbk][3] + t4[3]) * inv);
        *(uint2*)&attn[mrow + h * 64 + (2 + d2) * 16 + quad * 4] = ov;
      }
    }
  }
}

// ---------------------------------------------------------------------------
extern "C" void kernel_launch(void* const* d_in, const int* in_sizes, int n_in,
                              void* d_out, int out_size, void* d_ws, size_t ws_size,
                              hipStream_t stream)
{
  const float* x  = (const float*)d_in[0];
  const float* wq = (const float*)d_in[1];
  const float* bq = (const float*)d_in[2];
  const float* wk = (const float*)d_in[3];
  const float* bk = (const float*)d_in[4];
  const float* wv = (const float*)d_in[5];
  const float* bv = (const float*)d_in[6];
  const float* wo = (const float*)d_in[7];
  const float* bo = (const float*)d_in[8];
  float* out = (float*)d_out;

  short* ws = (short*)d_ws;
  const size_t M4 = (size_t)M_DIM * E_DIM;   // 4M elems
  const size_t M1 = (size_t)E_DIM * E_DIM;   // 1M elems
  short* aws  = ws;          // attn out fp16, live until gemm_out
  short* woh  = aws + M4;    // wo fp16, live until gemm_out
  short* xh   = woh + M1;
  short* wqh  = xh + M4;
  short* wkh  = wqh + M1;
  short* wvh  = wkh + M1;
  short* qws  = wvh + M1;
  short* kws  = qws + M4;
  short* vtws = kws + M4;    // end = 24M shorts = 48 MB

  convert_all<<<8192, 256, 0, stream>>>(x, wq, wk, wv, wo, xh, wqh, wkh, wvh, woh);
  gemm_qkv<<<dim3(24, 32), 256, 0, stream>>>(xh, wqh, wkh, wvh, bq, bk, bv,
                                             qws, kws, vtws);
  attn_mfma<<<dim3(32, 32), 256, 0, stream>>>(qws, kws, vtws, aws);
  gemm_out_fused<<<dim3(8, 32), 512, 0, stream>>>(aws, woh, bo, out);
}

// Round 6
// 192.621 us; speedup vs baseline: 1.0649x; 1.0595x over previous
//
#include <hip/hip_runtime.h>
#include <cstddef>
#include <cstdint>

#define T_DIM 2048
#define E_DIM 1024
#define M_DIM 4096   // T*B rows, row index = t*2 + b

typedef __attribute__((ext_vector_type(8))) short short8;      // 8 fp16 bit-patterns
typedef __attribute__((ext_vector_type(8))) _Float16 half8;    // mfma f16 A/B (x32)
typedef __attribute__((ext_vector_type(4))) _Float16 half4;    // mfma f16 A/B (x16)
typedef __attribute__((ext_vector_type(4))) float f32x4;       // mfma C/D

__device__ __forceinline__ short f16_bits(float v) {
  return __builtin_bit_cast(short, (_Float16)v);
}
__device__ __forceinline__ unsigned int pk2(float a, float b) {
  return __builtin_bit_cast(unsigned int, __builtin_amdgcn_cvt_pkrtz(a, b));
}
__device__ __forceinline__ half8 h8(short8 s) { return __builtin_bit_cast(half8, s); }

// async global->LDS, 16B per lane; LDS dest = wave-uniform base + lane*16
__device__ __forceinline__ void gl_lds16(const short* g, const short* l) {
  __builtin_amdgcn_global_load_lds(
      (const __attribute__((address_space(1))) unsigned int*)g,
      (__attribute__((address_space(3))) unsigned int*)l, 16, 0, 0);
}

// ---------------------------------------------------------------------------
// fp32 -> fp16 (RNE). blocks: [0,4096) x ; then 1024 each wq, wk, wv, wo.
// ---------------------------------------------------------------------------
__global__ __launch_bounds__(256) void convert_all(
    const float* __restrict__ x, const float* __restrict__ wq,
    const float* __restrict__ wk, const float* __restrict__ wv,
    const float* __restrict__ wo,
    short* __restrict__ xh, short* __restrict__ wqh, short* __restrict__ wkh,
    short* __restrict__ wvh, short* __restrict__ woh)
{
  const int bid = blockIdx.x;
  const float* in; short* hi; int base;
  if (bid < 4096)      { in = x;  hi = xh;  base = 0;    }
  else if (bid < 5120) { in = wq; hi = wqh; base = 4096; }
  else if (bid < 6144) { in = wk; hi = wkh; base = 5120; }
  else if (bid < 7168) { in = wv; hi = wvh; base = 6144; }
  else                 { in = wo; hi = woh; base = 7168; }
  const int i = (bid - base) * 256 + threadIdx.x;     // float4 index
  float4 v = ((const float4*)in)[i];
  uint2 p;
  p.x = (unsigned short)f16_bits(v.x) | ((unsigned int)(unsigned short)f16_bits(v.y) << 16);
  p.y = (unsigned short)f16_bits(v.z) | ((unsigned int)(unsigned short)f16_bits(v.w) << 16);
  ((uint2*)hi)[i] = p;
}

// ---------------------------------------------------------------------------
// Fused QKV GEMM, fp16, BK=64 (round-2 proven version). V emitted d-major
// ([bh][d][T]) via the Tb transpose epilogue.
// ---------------------------------------------------------------------------
__global__ __launch_bounds__(256) void gemm_qkv(
    const short* __restrict__ xh,
    const short* __restrict__ wqh, const short* __restrict__ wkh,
    const short* __restrict__ wvh,
    const float* __restrict__ bq, const float* __restrict__ bk,
    const float* __restrict__ bv,
    short* __restrict__ qo, short* __restrict__ ko, short* __restrict__ vto)
{
  __shared__ __align__(16) short smem[128 * 64 * 2];   // Ah | Wh ; Tb overlays
  short* Ah = smem;
  short* Wh = smem + 8192;
  const int tid = threadIdx.x;
  const int lane = tid & 63;
  const int w = tid >> 6;
  const int quad = lane >> 4;
  const int l15 = lane & 15;
  const int sel = blockIdx.x >> 3;
  const int n0 = (blockIdx.x & 7) * 128;
  const int m0 = blockIdx.y * 128;

  const short* wsel = sel == 0 ? wqh : sel == 1 ? wkh : wvh;
  const float* bias = sel == 0 ? bq : sel == 1 ? bk : bv;
  const float scale = sel == 0 ? 0.125f * 1.44269504088896f : 1.0f;

  const short* gsrc = (w < 2) ? xh : wsel;
  short* lbuf = (w < 2) ? Ah : Wh;
  const int rbase = (w < 2) ? m0 : n0;
  const int lrow8 = lane >> 3;
  const int gph8 = lane & 7;
  const int kg = (gph8 - lrow8) & 7;    // global k-group this lane stages

  f32x4 zero = {0.f, 0.f, 0.f, 0.f};
  f32x4 acc[4][4];
#pragma unroll
  for (int i = 0; i < 4; ++i)
#pragma unroll
    for (int j = 0; j < 4; ++j) acc[i][j] = zero;

  const int wm = w & 1, wn = w >> 1;

  for (int k0 = 0; k0 < E_DIM; k0 += 64) {
    __syncthreads();
#pragma unroll
    for (int jj = 0; jj < 8; ++jj) {
      int j = (w & 1) * 8 + jj;       // 16 staging insts per matrix, 2 waves
      int r = j * 8 + lrow8;          // 0..127
      gl_lds16(gsrc + (size_t)(rbase + r) * E_DIM + k0 + kg * 8, lbuf + j * 512);
    }
    __syncthreads();
#pragma unroll
    for (int ks = 0; ks < 2; ++ks) {
      short8 ahf[4];
#pragma unroll
      for (int i = 0; i < 4; ++i) {
        int r = wm * 64 + i * 16 + l15;
        ahf[i] = *(const short8*)&Ah[r * 64 + ((ks * 4 + quad + r) & 7) * 8];
      }
#pragma unroll
      for (int j = 0; j < 4; ++j) {
        int r = wn * 64 + j * 16 + l15;
        short8 bhf = *(const short8*)&Wh[r * 64 + ((ks * 4 + quad + r) & 7) * 8];
#pragma unroll
        for (int i = 0; i < 4; ++i)
          acc[i][j] = __builtin_amdgcn_mfma_f32_16x16x32_f16(h8(ahf[i]), h8(bhf), acc[i][j], 0, 0, 0);
      }
    }
  }

  if (sel < 2) {
#pragma unroll
    for (int j = 0; j < 4; ++j) {
      const int gc = n0 + wn * 64 + j * 16 + l15;
      const float bb = bias[gc];
      const int h = gc >> 6, d = gc & 63;
      short* dst = sel == 0 ? qo : ko;
#pragma unroll
      for (int i = 0; i < 4; ++i)
#pragma unroll
        for (int reg = 0; reg < 4; ++reg) {
          const int gm = m0 + wm * 64 + i * 16 + quad * 4 + reg;
          const float val = (acc[i][j][reg] + bb) * scale;
          const int t = gm >> 1, b = gm & 1;
          dst[((size_t)(b * 16 + h) * T_DIM + t) * 64 + d] = f16_bits(val);
        }
    }
  } else {
    short* Tb = smem;   // 64 * 128 * 2B = 16KB
    const int by = blockIdx.y;
#pragma unroll
    for (int R = 0; R < 2; ++R) {
      __syncthreads();
      if (wn == R) {
#pragma unroll
        for (int j = 0; j < 4; ++j) {
          const int nl = j * 16 + l15;
          const int gc = n0 + R * 64 + nl;
          const float bb = bias[gc];
#pragma unroll
          for (int i = 0; i < 4; ++i) {
            const int tp = wm * 32 + i * 8 + quad * 2;        // t' base (even)
            unsigned int lo = pk2(acc[i][j][0] + bb, acc[i][j][2] + bb);
            unsigned int hi = pk2(acc[i][j][1] + bb, acc[i][j][3] + bb);
            const int g0 = tp >> 3;
            const int sub = tp & 7;
            *(unsigned int*)&Tb[nl * 128 + ((g0 + nl) & 15) * 8 + sub] = lo;
            *(unsigned int*)&Tb[nl * 128 + ((g0 + 8 + nl) & 15) * 8 + sub] = hi;
          }
        }
      }
      __syncthreads();
#pragma unroll
      for (int ii = 0; ii < 4; ++ii) {
        const int n = w * 16 + ii * 4 + quad;
        const int g = (l15 - n) & 15;
        short8 vvec = *(const short8*)&Tb[n * 128 + l15 * 8];
        const int gc = n0 + R * 64 + n;
        const int h = gc >> 6, d = gc & 63;
        const int b = g >> 3;
        const int t = by * 64 + (g & 7) * 8;
        *(short8*)&vto[((size_t)(b * 16 + h) * 64 + d) * T_DIM + t] = vvec;
      }
    }
  }
}

// ---------------------------------------------------------------------------
// Output projection v2 — occupancy-first restructure (r5 post-mortem: old
// split-K version was 1 block/CU, 64KB LDS, 3-barrier combine, 8 K-steps).
// Now: 64x128 tiles, grid (8,64)=512 blocks (2/CU), 256 thr, 24KB LDS,
// serial K=1024 (16 steps), direct bias+fp32 epilogue. Index math is the
// qkv staging/fragment pattern verbatim. XCD = bx -> one 256KB W-panel per
// XCD (L2-resident), A streamed.
// ---------------------------------------------------------------------------
__global__ __launch_bounds__(256) void gemm_out_v2(
    const short* __restrict__ attn, const short* __restrict__ woh,
    const float* __restrict__ bo, float* __restrict__ out)
{
  __shared__ __align__(16) short smem[12288];   // Ah 64x64 (8KB) | Wh 128x64 (16KB)
  short* Ah = smem;
  short* Wh = smem + 4096;
  const int tid = threadIdx.x;
  const int lane = tid & 63;
  const int w = tid >> 6;          // 0..3 = wn (4-way N split)
  const int quad = lane >> 4;
  const int l15 = lane & 15;
  const int n0 = blockIdx.x * 128;
  const int m0 = blockIdx.y * 64;

  const int lrow8 = lane >> 3;
  const int gph8 = lane & 7;
  const int kg = (gph8 - lrow8) & 7;

  f32x4 zero = {0.f, 0.f, 0.f, 0.f};
  f32x4 acc[4][2];
#pragma unroll
  for (int i = 0; i < 4; ++i)
#pragma unroll
    for (int j = 0; j < 2; ++j) acc[i][j] = zero;

  for (int k0 = 0; k0 < E_DIM; k0 += 64) {
    __syncthreads();
    if (w < 2) {                    // stage A: 8 row-groups, 4 per wave
#pragma unroll
      for (int jj = 0; jj < 4; ++jj) {
        int j = w * 4 + jj;
        int r = j * 8 + lrow8;      // 0..63
        gl_lds16(attn + (size_t)(m0 + r) * E_DIM + k0 + kg * 8, Ah + j * 512);
      }
    } else {                        // stage W: 16 row-groups, 8 per wave
#pragma unroll
      for (int jj = 0; jj < 8; ++jj) {
        int j = (w - 2) * 8 + jj;
        int r = j * 8 + lrow8;      // 0..127
        gl_lds16(woh + (size_t)(n0 + r) * E_DIM + k0 + kg * 8, Wh + j * 512);
      }
    }
    __syncthreads();
#pragma unroll
    for (int ks = 0; ks < 2; ++ks) {
      short8 ahf[4];
#pragma unroll
      for (int i = 0; i < 4; ++i) {
        int r = i * 16 + l15;       // all 64 A-rows
        ahf[i] = *(const short8*)&Ah[r * 64 + ((ks * 4 + quad + r) & 7) * 8];
      }
#pragma unroll
      for (int j = 0; j < 2; ++j) {
        int r = w * 32 + j * 16 + l15;   // this wave's 32 W-rows
        short8 bhf = *(const short8*)&Wh[r * 64 + ((ks * 4 + quad + r) & 7) * 8];
#pragma unroll
        for (int i = 0; i < 4; ++i)
          acc[i][j] = __builtin_amdgcn_mfma_f32_16x16x32_f16(h8(ahf[i]), h8(bhf), acc[i][j], 0, 0, 0);
      }
    }
  }

#pragma unroll
  for (int j = 0; j < 2; ++j) {
    const int gc = n0 + w * 32 + j * 16 + l15;
    const float bb = bo[gc];
#pragma unroll
    for (int i = 0; i < 4; ++i)
#pragma unroll
      for (int reg = 0; reg < 4; ++reg) {
        const int gm = m0 + i * 16 + quad * 4 + reg;
        out[(size_t)gm * E_DIM + gc] = acc[i][j][reg] + bb;
      }
  }
}

// ---------------------------------------------------------------------------
// Flash attention v5 (round-2 verbatim, measured 52.0 us) — d-major V,
// ring3, vmcnt(4) waits, XCD remap, setprio. v6/v7/v8 experiments reverted
// (r3: tr-read fences spilled; r4: q-split LDS-BW bound; r5: ring2 slower).
// ---------------------------------------------------------------------------
__global__ __launch_bounds__(256, 2) void attn_mfma(
    const short* __restrict__ q, const short* __restrict__ k,
    const short* __restrict__ vt, short* __restrict__ attn)
{
  __shared__ __align__(16) short SMEM[32768];   // 64 KB
  __shared__ float l_red[4][128];
  short* Qs = SMEM;            // 16 KB, dead after qa load
  short* KV = SMEM + 8192;     // ring[3] x wave[4] x (K 1024 + V 1024 shorts)

  const int tid = threadIdx.x;
  const int lane = tid & 63;
  const int w = tid >> 6;
  const int quad = lane >> 4;
  const int l15 = lane & 15;

  // XCD-aware remap: dispatch-linear id fid -> XCD fid%8.
  const int fid = blockIdx.y * 16 + blockIdx.x;
  const int bhid = fid & 31;
  const int t0 = (fid >> 5) * 128;
  const int b = bhid >> 4, h = bhid & 15;

  const short* qb = q + (size_t)bhid * T_DIM * 64;
  const short* kb = k + (size_t)bhid * T_DIM * 64;
  const short* vb = vt + (size_t)bhid * 64 * T_DIM;

  const int lrow8 = lane >> 3;
  const int gph8 = lane & 7;

  // ---- stage Q tile [128][64] ----
#pragma unroll
  for (int jj = 0; jj < 4; ++jj) {
    int j = w * 4 + jj;
    int r = j * 8 + lrow8;
    int gl = (gph8 - (r >> 1)) & 7;
    gl_lds16(qb + (size_t)(t0 + r) * 64 + gl * 8, Qs + j * 512);
  }

  // ---- stage K/V chunks 0,1 into rings 0,1 (wave-private slices) ----
  const int kg = (gph8 - lrow8) & 7;
  const int vd = lane >> 1, vh = lane & 1;
#pragma unroll
  for (int c0 = 0; c0 < 2; ++c0) {
    short* slot = KV + c0 * 8192 + w * 2048;
    const int sg = c0 * 64 + w * 16;
    gl_lds16(kb + (size_t)(sg + lrow8) * 64 + kg * 8, slot);
    gl_lds16(kb + (size_t)(sg + lrow8 + 8) * 64 + kg * 8, slot + 512);
    gl_lds16(vb + (size_t)vd * T_DIM + sg + vh * 8, slot + 1024);
    gl_lds16(vb + (size_t)(vd + 32) * T_DIM + sg + vh * 8, slot + 1536);
  }
  __syncthreads();

  // ---- register-cache Q B-fragments ----
  short8 qa[8][2];
#pragma unroll
  for (int qbk = 0; qbk < 8; ++qbk)
#pragma unroll
    for (int st = 0; st < 2; ++st) {
      int r = qbk * 16 + l15;
      int idx = r * 64 + (((st * 4 + quad) + (r >> 1)) & 7) * 8;
      qa[qbk][st] = *(const short8*)&Qs[idx];
    }

  f32x4 zero = {0.f, 0.f, 0.f, 0.f};
  f32x4 acc[4][8];               // [dblk][qbk] : O^T partial over own s-subset
  float l_part[8];
#pragma unroll
  for (int d = 0; d < 4; ++d)
#pragma unroll
    for (int qb2 = 0; qb2 < 8; ++qb2) acc[d][qb2] = zero;
#pragma unroll
  for (int i = 0; i < 8; ++i) l_part[i] = 0.f;

  for (int c = 0; c < 32; ++c) {
    if (c >= 2) {
      if (c == 31) __builtin_amdgcn_s_waitcnt(0x0F70);   // vmcnt(0)
      else         __builtin_amdgcn_s_waitcnt(0x0F74);   // vmcnt(4)
    }
    const short* slot = KV + (c % 3) * 8192 + w * 2048;

    short8 kf[2];
#pragma unroll
    for (int st = 0; st < 2; ++st)
      kf[st] = *(const short8*)&slot[l15 * 64 + (((st * 4 + quad) + l15) & 7) * 8];
    uint2 vfu[4];
#pragma unroll
    for (int dblk = 0; dblk < 4; ++dblk)
      vfu[dblk] = *(const uint2*)&slot[1024 + (dblk * 16 + l15) * 16 + quad * 4];

    if (c < 30) {
      short* nslot = KV + ((c + 2) % 3) * 8192 + w * 2048;
      const int sg = (c + 2) * 64 + w * 16;
      gl_lds16(kb + (size_t)(sg + lrow8) * 64 + kg * 8, nslot);
      gl_lds16(kb + (size_t)(sg + lrow8 + 8) * 64 + kg * 8, nslot + 512);
      gl_lds16(vb + (size_t)vd * T_DIM + sg + vh * 8, nslot + 1024);
      gl_lds16(vb + (size_t)(vd + 32) * T_DIM + sg + vh * 8, nslot + 1536);
    }

    __builtin_amdgcn_s_setprio(1);
    uint2 pb[8];
#pragma unroll
    for (int qbk = 0; qbk < 8; ++qbk) {
      f32x4 s = zero;
      s = __builtin_amdgcn_mfma_f32_16x16x32_f16(h8(kf[0]), h8(qa[qbk][0]), s, 0, 0, 0);
      s = __builtin_amdgcn_mfma_f32_16x16x32_f16(h8(kf[1]), h8(qa[qbk][1]), s, 0, 0, 0);
      float p0 = __builtin_amdgcn_exp2f(s[0]);
      float p1 = __builtin_amdgcn_exp2f(s[1]);
      float p2 = __builtin_amdgcn_exp2f(s[2]);
      float p3 = __builtin_amdgcn_exp2f(s[3]);
      l_part[qbk] += (p0 + p1) + (p2 + p3);
      pb[qbk].x = pk2(p0, p1);
      pb[qbk].y = pk2(p2, p3);
    }

#pragma unroll
    for (int dblk = 0; dblk < 4; ++dblk) {
      half4 va = __builtin_bit_cast(half4, vfu[dblk]);
#pragma unroll
      for (int qbk = 0; qbk < 8; ++qbk)
        acc[dblk][qbk] = __builtin_amdgcn_mfma_f32_16x16x16f16(
            va, __builtin_bit_cast(half4, pb[qbk]), acc[dblk][qbk], 0, 0, 0);
    }
    __builtin_amdgcn_s_setprio(0);
  }

  // ---- l reduce over quads, publish per-wave ----
#pragma unroll
  for (int qbk = 0; qbk < 8; ++qbk) {
    float l = l_part[qbk];
    l += __shfl_xor(l, 16);
    l += __shfl_xor(l, 32);
    if (quad == 0) l_red[w][qbk * 16 + l15] = l;
  }

  // ---- pairwise O reduce via 64 KB LDS scratch (overlays Qs+KV) ----
  f32x4* Osc = (f32x4*)SMEM;     // regions of 1024/2048 f32x4
  __syncthreads();               // all waves out of the main loop
  if (w & 1) {                   // w1 -> region0, w3 -> region1
    f32x4* dst = Osc + (w >> 1) * 2048;
#pragma unroll
    for (int dblk = 0; dblk < 4; ++dblk)
#pragma unroll
      for (int qbk = 0; qbk < 8; ++qbk)
        dst[(dblk * 8 + qbk) * 64 + lane] = acc[dblk][qbk];
  }
  __syncthreads();
  if (!(w & 1)) {                // w0 += region0 (all dblk), w2 += region1
    f32x4* src = Osc + (w >> 1) * 2048;
#pragma unroll
    for (int dblk = 0; dblk < 4; ++dblk)
#pragma unroll
      for (int qbk = 0; qbk < 8; ++qbk) {
        f32x4 t = src[(dblk * 8 + qbk) * 64 + lane];
        acc[dblk][qbk][0] += t[0]; acc[dblk][qbk][1] += t[1];
        acc[dblk][qbk][2] += t[2]; acc[dblk][qbk][3] += t[3];
      }
  }
  __syncthreads();
  // swap-publish: w2 gives its dblk 0,1 to w0; w0 gives its dblk 2,3 to w2
  if (w == 2) {
#pragma unroll
    for (int d2 = 0; d2 < 2; ++d2)
#pragma unroll
      for (int qbk = 0; qbk < 8; ++qbk)
        Osc[(d2 * 8 + qbk) * 64 + lane] = acc[d2][qbk];
  }
  if (w == 0) {
#pragma unroll
    for (int d2 = 0; d2 < 2; ++d2)
#pragma unroll
      for (int qbk = 0; qbk < 8; ++qbk)
        Osc[1024 + (d2 * 8 + qbk) * 64 + lane] = acc[2 + d2][qbk];
  }
  __syncthreads();
  if (w == 0) {                  // stores dblk 0,1
#pragma unroll
    for (int qbk = 0; qbk < 8; ++qbk) {
      const int qq = qbk * 16 + l15;
      const float lsum = l_red[0][qq] + l_red[1][qq] + l_red[2][qq] + l_red[3][qq];
      const float inv = 1.f / lsum;
      const int t = t0 + qq;
      const size_t mrow = (size_t)(t * 2 + b) * E_DIM;
#pragma unroll
      for (int d2 = 0; d2 < 2; ++d2) {
        f32x4 t4 = Osc[(d2 * 8 + qbk) * 64 + lane];
        uint2 ov;
        ov.x = pk2((acc[d2][qbk][0] + t4[0]) * inv, (acc[d2][qbk][1] + t4[1]) * inv);
        ov.y = pk2((acc[d2][qbk][2] + t4[2]) * inv, (acc[d2][qbk][3] + t4[3]) * inv);
        *(uint2*)&attn[mrow + h * 64 + d2 * 16 + quad * 4] = ov;
      }
    }
  }
  if (w == 2) {                  // stores dblk 2,3
#pragma unroll
    for (int qbk = 0; qbk < 8; ++qbk) {
      const int qq = qbk * 16 + l15;
      const float lsum = l_red[0][qq] + l_red[1][qq] + l_red[2][qq] + l_red[3][qq];
      const float inv = 1.f / lsum;
      const int t = t0 + qq;
      const size_t mrow = (size_t)(t * 2 + b) * E_DIM;
#pragma unroll
      for (int d2 = 0; d2 < 2; ++d2) {
        f32x4 t4 = Osc[1024 + (d2 * 8 + qbk) * 64 + lane];
        uint2 ov;
        ov.x = pk2((acc[2 + d2][qbk][0] + t4[0]) * inv, (acc[2 + d2][qbk][1] + t4[1]) * inv);
        ov.y = pk2((acc[2 + d2][qbk][2] + t4[2]) * inv, (acc[2 + d2][qbk][3] + t4[3]) * inv);
        *(uint2*)&attn[mrow + h * 64 + (2 + d2) * 16 + quad * 4] = ov;
      }
    }
  }
}

// ---------------------------------------------------------------------------
extern "C" void kernel_launch(void* const* d_in, const int* in_sizes, int n_in,
                              void* d_out, int out_size, void* d_ws, size_t ws_size,
                              hipStream_t stream)
{
  const float* x  = (const float*)d_in[0];
  const float* wq = (const float*)d_in[1];
  const float* bq = (const float*)d_in[2];
  const float* wk = (const float*)d_in[3];
  const float* bk = (const float*)d_in[4];
  const float* wv = (const float*)d_in[5];
  const float* bv = (const float*)d_in[6];
  const float* wo = (const float*)d_in[7];
  const float* bo = (const float*)d_in[8];
  float* out = (float*)d_out;

  short* ws = (short*)d_ws;
  const size_t M4 = (size_t)M_DIM * E_DIM;   // 4M elems
  const size_t M1 = (size_t)E_DIM * E_DIM;   // 1M elems
  short* aws  = ws;          // attn out fp16, live until gemm_out
  short* woh  = aws + M4;    // wo fp16, live until gemm_out
  short* xh   = woh + M1;
  short* wqh  = xh + M4;
  short* wkh  = wqh + M1;
  short* wvh  = wkh + M1;
  short* qws  = wvh + M1;
  short* kws  = qws + M4;
  short* vtws = kws + M4;    // end = 24M shorts = 48 MB

  convert_all<<<8192, 256, 0, stream>>>(x, wq, wk, wv, wo, xh, wqh, wkh, wvh, woh);
  gemm_qkv<<<dim3(24, 32), 256, 0, stream>>>(xh, wqh, wkh, wvh, bq, bk, bv,
                                             qws, kws, vtws);
  attn_mfma<<<dim3(16, 32), 256, 0, stream>>>(qws, kws, vtws, aws);
  gemm_out_v2<<<dim3(8, 64), 256, 0, stream>>>(aws, woh, bo, out);
}